// Round 4
// baseline (205251.025 us; speedup 1.0000x reference)
//
#include <hip/hip_runtime.h>
#include <cstdint>

// TinyVanillaRNN: T=16384 sequential steps h = tanh(U[:,x_t] + W h + bh);
// logits[t] = V h_t + by. out = [logits (T*O) | h_T (H)], fp32.
//
// R7 = R4 + hang-proofing. R4 (single-XCD handoff) has never reached HW:
// rounds 1-2 were broker timeouts, round 3 a Trio nursery exception that
// could mask a kernel hang. R4's only infinite-spin hazard is the
// assumption "sc0 load bypasses L1 and sees plain stores via the XCD-local
// L2". R7 bounds every poll: after 2^16 failed sc0 probes (>>1000x any
// legitimate wait) the thread STICKILY falls back to agent-scope atomic
// loads (the R3 path, known-correct on this chip). If the sc0 theory is
// right, the fallback never fires and this is exactly R4; if wrong, the
// kernel completes at ~R3 speed and the counters refute the theory instead
// of hanging.
//
// R4 mechanism: elect 32 worker blocks on ONE XCD, h-handoff through the
// XCD-local shared L2:
//   - grid = 256 blocks; each reads HW_REG_XCC_ID, takes a per-XCD slot
//     (device-scope atomicAdd); first XCD to fill 32 slots wins (atomicCAS).
//     Pigeonhole over 256 co-resident blocks (1 block/CU at these bounds)
//     guarantees a winner; losers exit; no election deadlock.
//   - publish: plain global_store_dwordx2 (write-through L1 -> dirty line in
//     the shared XCD L2, never leaves the XCD).
//   - poll: global_load_dwordx4 sc0 (L1 bypass, local-L2 hit) on the 16B
//     tagged pair. No sc1 in the steady-state loop.
// Compute dataflow unchanged from R3: thread = 4 W-rows x 16 k's in VGPRs,
// 4x ds_read_b128 h delivery, fused select+butterfly reduce, V logits
// computed in the post-publish window.

constexpr int T_STEPS = 16384;
constexpr int D_DIM   = 512;
constexpr int H_DIM   = 1024;
constexpr int O_DIM   = 512;
constexpr int NWORK   = 32;    // worker blocks, all on one XCD
constexpr int NGRID   = 256;   // oversubscribe: some XCD surely fills 32
constexpr int NTHR    = 512;
constexpr int SPIN_MAX = 1 << 16;   // ~20M cyc; legit waits are ~1e3 cyc
constexpr int CTL_OFF = 2 * H_DIM * (int)sizeof(unsigned long long);  // 16 KiB

typedef unsigned int u32x4 __attribute__((ext_vector_type(4)));

__device__ __forceinline__ float fast_tanh(float x) {
    // 1 - 2/(e^{2x}+1); saturates exactly at +-1 for large |x|
    float e = __expf(2.f * x);
    return 1.f - 2.f / (e + 1.f);
}

__device__ __forceinline__ float hsum4(const float4& v) {
    return (v.x + v.y) + (v.z + v.w);
}

__device__ __forceinline__ int xcc_id() {
    unsigned x;
    asm volatile("s_getreg_b32 %0, hwreg(HW_REG_XCC_ID)" : "=s"(x));
    return (int)(x & 0xfu);
}

// 16B tagged-pair poll: sc0 = miss L1, hit the XCD-local L2 where producer
// stores land. Deliberately NO sc1 -> the load never leaves the XCD.
__device__ __forceinline__ u32x4 ld16_sc0(const unsigned long long* p) {
    u32x4 v;
    asm volatile("global_load_dwordx4 %0, %1, off sc0\n\t"
                 "s_waitcnt vmcnt(0)"
                 : "=v"(v)
                 : "v"((unsigned long long)p)
                 : "memory");
    return v;
}

// Publish: plain store -> write-through L1 -> dirty line in shared XCD L2.
__device__ __forceinline__ void st64_l2(unsigned long long* p, unsigned long long d) {
    asm volatile("global_store_dwordx2 %0, %1, off"
                 :: "v"((unsigned long long)p), "v"(d)
                 : "memory");
}

// Bounded sc0 poll with sticky agent-scope fallback. Returns {val0, val1}.
__device__ __forceinline__ float2 poll_pair(const unsigned long long* pp,
                                            unsigned want, bool& use_sc1) {
    unsigned v0 = 0, v1 = 0;
    if (!use_sc1) {
        int spins = 0;
        for (;;) {
            u32x4 q = ld16_sc0(pp);          // {val0, tag0, val1, tag1}
            if (q.y == want && q.w == want) {
                v0 = q.x; v1 = q.z;
                break;
            }
            if (++spins >= SPIN_MAX) { use_sc1 = true; break; }
        }
    }
    if (use_sc1) {
        unsigned long long q0, q1;
        do {
            q0 = __hip_atomic_load(pp + 0, __ATOMIC_RELAXED,
                                   __HIP_MEMORY_SCOPE_AGENT);
            q1 = __hip_atomic_load(pp + 1, __ATOMIC_RELAXED,
                                   __HIP_MEMORY_SCOPE_AGENT);
        } while ((unsigned)(q0 >> 32) != want || (unsigned)(q1 >> 32) != want);
        v0 = (unsigned)q0; v1 = (unsigned)q1;
    }
    return make_float2(__uint_as_float(v0), __uint_as_float(v1));
}

__global__ __launch_bounds__(NTHR, 2)
void rnn_fused(const int* __restrict__ xs, const float* __restrict__ h0,
               const float* __restrict__ U, const float* __restrict__ W,
               const float* __restrict__ V, const float* __restrict__ bh,
               const float* __restrict__ by, float* __restrict__ out,
               unsigned long long* __restrict__ htag, int* __restrict__ ctl)
{
    const int tid = threadIdx.x;

    // ---- XCD election: first XCD to register NWORK blocks wins ----
    // ctl[0..7] = per-XCD registration counters, ctl[8] = winner (0 = unset,
    // xcd+1 = decided). All agent-scope (must cross XCDs, one-time cost).
    __shared__ int s_slot;
    if (tid == 0) {
        const int xcd = xcc_id();
        int my = -1;
        const int slot = atomicAdd(&ctl[xcd], 1);
        if (slot < NWORK) {
            if (slot == NWORK - 1) atomicCAS(&ctl[8], 0, xcd + 1);
            int w;
            do {
                w = __hip_atomic_load(&ctl[8], __ATOMIC_RELAXED,
                                      __HIP_MEMORY_SCOPE_AGENT);
            } while (w == 0);
            if (w == xcd + 1) my = slot;
        }
        s_slot = my;
    }
    __syncthreads();
    const int b = s_slot;          // worker id 0..31, or -1
    if (b < 0) return;

    const int w = tid >> 6;        // wave 0..7
    const int l = tid & 63;        // lane
    bool use_sc1 = false;          // sticky poll-fallback flag

    // h in LDS: 64 chunks x 16 floats; quad q of chunk c stored at dword
    // 16c + 4*(q ^ ((c>>1)&3)) (permutation inside the 64B chunk -> no
    // padding; spreads reads over all 32 banks).
    __shared__ float hl[2][H_DIM];

    // ---- W fragment: rows wr0..wr0+3, k in [16l, 16l+16) ----
    const int wr0 = b * 32 + w * 4;
    float4 wreg[4][4];
#pragma unroll
    for (int j = 0; j < 4; ++j)
#pragma unroll
        for (int q = 0; q < 4; ++q)
            wreg[j][q] = *(const float4*)(W + (size_t)(wr0 + j) * H_DIM + 16 * l + 4 * q);
    const float bh_r = bh[wr0 + (l & 3)];
    const int   urow = wr0 + (l & 3);

    // ---- V fragment: rows vr0, vr0+1, same k-chunk ----
    const int vr0 = b * 16 + w * 2;
    float4 vreg[2][4];
#pragma unroll
    for (int m = 0; m < 2; ++m)
#pragma unroll
        for (int q = 0; q < 4; ++q)
            vreg[m][q] = *(const float4*)(V + (size_t)(vr0 + m) * H_DIM + 16 * l + 4 * q);
    const float by_r = by[vr0 + (l & 1)];

    // ---- LDS addresses (dwords) ----
    int rdw[4];                    // lane reads chunk l, logical quads 0..3
#pragma unroll
    for (int q = 0; q < 4; ++q)
        rdw[q] = 16 * l + 4 * (q ^ ((l >> 1) & 3));
    const int c   = tid >> 3;                       // staged chunk
    const int qw  = (tid >> 1) & 3;                 // staged quad
    const int wdw = 16 * c + 4 * (qw ^ ((c >> 1) & 3)) + 2 * (tid & 1);  // 8B aligned

    const bool o1 = (l & 1) != 0, o2 = (l & 2) != 0;

    for (int t = 0; t < T_STEPS; ++t) {
        const int sb = (~t) & 1;
        float* hb = hl[sb];

        // independent prefetch chain: xs[t] -> U gather (hidden under poll)
        const int   xt = xs[t];
        const float uv = U[(size_t)urow * D_DIM + xt];

        // ---- acquire h^{(t)}: each thread polls its 16B tagged pair ----
        float2 hpair;
        if (t == 0) {
            hpair = *(const float2*)(h0 + 2 * tid);
        } else {
            hpair = poll_pair(htag + (size_t)((t - 1) & 1) * H_DIM + 2 * tid,
                              (unsigned)(t - 1), use_sc1);
        }
        *(float2*)&hb[wdw] = hpair;
        __syncthreads();

        // ---- critical path: 16 h floats, 64 FMAs, fused select+reduce ----
        float4 h4[4];
#pragma unroll
        for (int q = 0; q < 4; ++q) h4[q] = *(const float4*)&hb[rdw[q]];

        float s[4];
#pragma unroll
        for (int j = 0; j < 4; ++j) {
            float4 a = make_float4(0.f, 0.f, 0.f, 0.f);
#pragma unroll
            for (int q = 0; q < 4; ++q) {
                a.x += wreg[j][q].x * h4[q].x;
                a.y += wreg[j][q].y * h4[q].y;
                a.z += wreg[j][q].z * h4[q].z;
                a.w += wreg[j][q].w * h4[q].w;
            }
            s[j] = hsum4(a);
        }
        // select+butterfly: lane l ends with full sum of row wr0 + (l&3)
        float A  = o1 ? s[1] : s[0], Ax = o1 ? s[0] : s[1];
        float B  = o1 ? s[3] : s[2], Bx = o1 ? s[2] : s[3];
        A += __shfl_xor(Ax, 1);
        B += __shfl_xor(Bx, 1);
        float Cv = o2 ? B : A, Cx = o2 ? A : B;
        Cv += __shfl_xor(Cx, 2);
        Cv += __shfl_xor(Cv, 4);
        Cv += __shfl_xor(Cv, 8);
        Cv += __shfl_xor(Cv, 16);
        Cv += __shfl_xor(Cv, 32);

        const float hv = fast_tanh(Cv + bh_r + uv);
        if (l < 4) {
            const unsigned long long pk =
                ((unsigned long long)(unsigned)t << 32) |
                (unsigned long long)__float_as_uint(hv);
            st64_l2(htag + (size_t)(t & 1) * H_DIM + wr0 + l, pk);
        }
        __builtin_amdgcn_sched_barrier(0);   // publish must not sink below V

        // ---- hidden window: logits[t-1] from h4 registers (h^{(t)}) ----
        if (t > 0) {
            float sv[2];
#pragma unroll
            for (int m = 0; m < 2; ++m) {
                float4 a = make_float4(0.f, 0.f, 0.f, 0.f);
#pragma unroll
                for (int q = 0; q < 4; ++q) {
                    a.x += vreg[m][q].x * h4[q].x;
                    a.y += vreg[m][q].y * h4[q].y;
                    a.z += vreg[m][q].z * h4[q].z;
                    a.w += vreg[m][q].w * h4[q].w;
                }
                sv[m] = hsum4(a);
            }
            float P  = o1 ? sv[1] : sv[0], Px = o1 ? sv[0] : sv[1];
            P += __shfl_xor(Px, 1);
            P += __shfl_xor(P, 2);
            P += __shfl_xor(P, 4);
            P += __shfl_xor(P, 8);
            P += __shfl_xor(P, 16);
            P += __shfl_xor(P, 32);
            if (l < 2) out[(size_t)(t - 1) * O_DIM + vr0 + l] = P + by_r;
        }
    }

    // ---- epilogue: h_T (tag T-1, parity 1) -> out tail + logits[T-1] ----
    {
        float2 hpair = poll_pair(
            htag + (size_t)((T_STEPS - 1) & 1) * H_DIM + 2 * tid,
            (unsigned)(T_STEPS - 1), use_sc1);
        if (b == 0)
            *(float2*)&out[(size_t)T_STEPS * O_DIM + 2 * tid] = hpair;

        float* hb = hl[1];             // free: loop's last stage used hl[0]
        *(float2*)&hb[wdw] = hpair;
        __syncthreads();
        float4 h4[4];
#pragma unroll
        for (int qq = 0; qq < 4; ++qq) h4[qq] = *(const float4*)&hb[rdw[qq]];
        float sv[2];
#pragma unroll
        for (int m = 0; m < 2; ++m) {
            float4 a = make_float4(0.f, 0.f, 0.f, 0.f);
#pragma unroll
            for (int qq = 0; qq < 4; ++qq) {
                a.x += vreg[m][qq].x * h4[qq].x;
                a.y += vreg[m][qq].y * h4[qq].y;
                a.z += vreg[m][qq].z * h4[qq].z;
                a.w += vreg[m][qq].w * h4[qq].w;
            }
            sv[m] = hsum4(a);
        }
        float P  = o1 ? sv[1] : sv[0], Px = o1 ? sv[0] : sv[1];
        P += __shfl_xor(Px, 1);
        P += __shfl_xor(P, 2);
        P += __shfl_xor(P, 4);
        P += __shfl_xor(P, 8);
        P += __shfl_xor(P, 16);
        P += __shfl_xor(P, 32);
        if (l < 2) out[(size_t)(T_STEPS - 1) * O_DIM + vr0 + l] = P + by_r;
    }
}

extern "C" void kernel_launch(void* const* d_in, const int* in_sizes, int n_in,
                              void* d_out, int out_size, void* d_ws, size_t ws_size,
                              hipStream_t stream) {
    const int*   xs = (const int*)d_in[0];
    const float* h0 = (const float*)d_in[1];
    const float* U  = (const float*)d_in[2];
    const float* W  = (const float*)d_in[3];
    const float* V  = (const float*)d_in[4];
    const float* bh = (const float*)d_in[5];
    const float* by = (const float*)d_in[6];
    float* out = (float*)d_out;

    // ws: htag[2][1024] u64 (16 KiB) | ctl[16] int (cnt[8], winner, pad).
    // Poison tag 0xAAAAAAAA never matches a step in [0,16384). The memsets
    // re-run on every graph replay, clearing the previous iteration's tags
    // (which WOULD otherwise alias valid step numbers).
    unsigned long long* htag = (unsigned long long*)d_ws;
    int* ctl = (int*)((char*)d_ws + CTL_OFF);
    hipMemsetAsync(d_ws, 0xAA, CTL_OFF, stream);
    hipMemsetAsync((char*)d_ws + CTL_OFF, 0, 16 * sizeof(int), stream);

    rnn_fused<<<NGRID, NTHR, 0, stream>>>(xs, h0, U, W, V, bh, by, out, htag, ctl);
}

// Round 5
// 24225.339 us; speedup vs baseline: 8.4726x; 8.4726x over previous
//
#include <hip/hip_runtime.h>
#include <cstdint>

// TinyVanillaRNN: T=16384 sequential steps h = tanh(U[:,x_t] + W h + bh);
// logits[t] = V h_t + by. out = [logits (T*O) | h_T (H)], fp32.
//
// R8: revert to R3's proven agent-scope (sc0+sc1 / LLC) handoff and shrink
// the poll PERIOD instead. R7 (single-XCD L2 handoff, sc0-only polls) was
// REFUTED on HW: passed but 205-294ms -- sc0 loads spin on stale L1 until
// chance eviction (~30k cy/step, high variance; FETCH collapsed to 4MB so
// the traffic stayed local, but visibility latency exploded). The only
// verified low-latency cross-block visibility is the agent-scope path
// (R3: 3350 cy/step).
//
// R3's step decomposed: store drain (~600cy) + poll detect (~1.5x poll
// period; period = one serialized LLC RTT ~650cy) + barrier slack (~0.5
// period) + LDS/compute/reduce (~600cy). R8 pipelines the poll 3-deep:
// three same-address global_load_dwordx4 sc0 sc1 in flight, check the
// oldest at s_waitcnt vmcnt(2), reissue. Period ~650 -> ~220cy; detect and
// barrier slack both shrink. One 16B load also replaces R3's two 8B atomic
// loads (producer's 8B atomic store commits value+tag together; a 16B load
// is a single L2-snapshot request, so no tearing).
// Inline-asm discipline: sched_barrier(0) after every asm waitcnt (guide
// rule #18); in-flight regs pinned live through the final drain waitcnt so
// regalloc can't reuse them while a load is pending.
//
// Compute dataflow unchanged from R3: 32 blocks x 512 threads; thread =
// 4 W-rows x 16 k's (64 W floats in VGPRs), 4x ds_read_b128 h delivery,
// fused select+butterfly reduce, V logits in the post-publish window.

constexpr int T_STEPS = 16384;
constexpr int D_DIM   = 512;
constexpr int H_DIM   = 1024;
constexpr int O_DIM   = 512;
constexpr int NBLK    = 32;
constexpr int NTHR    = 512;

typedef unsigned int u32x4 __attribute__((ext_vector_type(4)));

__device__ __forceinline__ float fast_tanh(float x) {
    // 1 - 2/(e^{2x}+1); saturates exactly at +-1 for large |x|
    float e = __expf(2.f * x);
    return 1.f - 2.f / (e + 1.f);
}

__device__ __forceinline__ float hsum4(const float4& v) {
    return (v.x + v.y) + (v.z + v.w);
}

// Issue one 16B tagged-pair load that bypasses L1 AND L2 (sc0 sc1) -> always
// observes the LLC, where agent-scope publishes land. NO waitcnt here; the
// caller pipelines several in flight.
#define POLL_ISSUE(reg, addr)                                          \
    asm volatile("global_load_dwordx4 %0, %1, off sc0 sc1"             \
                 : "=v"(reg) : "v"((unsigned long long)(addr)))

// 3-deep pipelined poll on one 16B tagged pair {val0,tag0,val1,tag1}.
// Wave-uniform exit (__all) like R3's divergent do-while, but the reload
// period is ~RTT/3 instead of RTT.
__device__ __forceinline__ float2 poll_pair3(const unsigned long long* pp,
                                             unsigned want) {
    u32x4 qa, qb, qc, r;
    POLL_ISSUE(qa, pp);
    POLL_ISSUE(qb, pp);
    POLL_ISSUE(qc, pp);
    for (;;) {
        asm volatile("s_waitcnt vmcnt(2)" ::: "memory");   // oldest (qa) done
        __builtin_amdgcn_sched_barrier(0);
        if (__all(qa.y == want && qa.w == want)) { r = qa; break; }
        POLL_ISSUE(qa, pp);
        asm volatile("s_waitcnt vmcnt(2)" ::: "memory");   // oldest (qb) done
        __builtin_amdgcn_sched_barrier(0);
        if (__all(qb.y == want && qb.w == want)) { r = qb; break; }
        POLL_ISSUE(qb, pp);
        asm volatile("s_waitcnt vmcnt(2)" ::: "memory");   // oldest (qc) done
        __builtin_amdgcn_sched_barrier(0);
        if (__all(qc.y == want && qc.w == want)) { r = qc; break; }
        POLL_ISSUE(qc, pp);
    }
    // Drain the still-in-flight loads BEFORE qa/qb/qc die: pinning them as
    // inputs keeps the registers live so regalloc can't hand them to other
    // values while a load is pending (in-flight-reuse hazard).
    asm volatile("s_waitcnt vmcnt(0)"
                 :: "v"(qa), "v"(qb), "v"(qc) : "memory");
    __builtin_amdgcn_sched_barrier(0);
    return make_float2(__uint_as_float(r.x), __uint_as_float(r.z));
}

__global__ __launch_bounds__(NTHR, 2)
void rnn_fused(const int* __restrict__ xs, const float* __restrict__ h0,
               const float* __restrict__ U, const float* __restrict__ W,
               const float* __restrict__ V, const float* __restrict__ bh,
               const float* __restrict__ by, float* __restrict__ out,
               unsigned long long* __restrict__ htag)
{
    const int b   = blockIdx.x;
    const int tid = threadIdx.x;
    const int w   = tid >> 6;      // wave 0..7
    const int l   = tid & 63;      // lane

    // h in LDS: 64 chunks x 16 floats; quad q of chunk c stored at dword
    // 16c + 4*(q ^ ((c>>1)&3)) (permutation inside the 64B chunk -> no
    // padding; spreads reads over all 32 banks).
    __shared__ float hl[2][H_DIM];

    // ---- W fragment: rows wr0..wr0+3, k in [16l, 16l+16) ----
    const int wr0 = b * 32 + w * 4;
    float4 wreg[4][4];
#pragma unroll
    for (int j = 0; j < 4; ++j)
#pragma unroll
        for (int q = 0; q < 4; ++q)
            wreg[j][q] = *(const float4*)(W + (size_t)(wr0 + j) * H_DIM + 16 * l + 4 * q);
    const float bh_r = bh[wr0 + (l & 3)];
    const int   urow = wr0 + (l & 3);

    // ---- V fragment: rows vr0, vr0+1, same k-chunk ----
    const int vr0 = b * 16 + w * 2;
    float4 vreg[2][4];
#pragma unroll
    for (int m = 0; m < 2; ++m)
#pragma unroll
        for (int q = 0; q < 4; ++q)
            vreg[m][q] = *(const float4*)(V + (size_t)(vr0 + m) * H_DIM + 16 * l + 4 * q);
    const float by_r = by[vr0 + (l & 1)];

    // ---- LDS addresses (dwords) ----
    int rdw[4];                    // lane reads chunk l, logical quads 0..3
#pragma unroll
    for (int q = 0; q < 4; ++q)
        rdw[q] = 16 * l + 4 * (q ^ ((l >> 1) & 3));
    const int c   = tid >> 3;                       // staged chunk
    const int qw  = (tid >> 1) & 3;                 // staged quad
    const int wdw = 16 * c + 4 * (qw ^ ((c >> 1) & 3)) + 2 * (tid & 1);  // 8B aligned

    const bool o1 = (l & 1) != 0, o2 = (l & 2) != 0;

    for (int t = 0; t < T_STEPS; ++t) {
        const int sb = (~t) & 1;
        float* hb = hl[sb];

        // independent prefetch chain: xs[t] -> U gather (hidden under poll)
        const int   xt = xs[t];
        const float uv = U[(size_t)urow * D_DIM + xt];

        // ---- acquire h^{(t)}: each thread polls its 16B tagged pair ----
        float2 hpair;
        if (t == 0) {
            hpair = *(const float2*)(h0 + 2 * tid);
        } else {
            hpair = poll_pair3(htag + (size_t)((t - 1) & 1) * H_DIM + 2 * tid,
                               (unsigned)(t - 1));
        }
        *(float2*)&hb[wdw] = hpair;
        __syncthreads();

        // ---- critical path: 16 h floats, 64 FMAs, fused select+reduce ----
        float4 h4[4];
#pragma unroll
        for (int q = 0; q < 4; ++q) h4[q] = *(const float4*)&hb[rdw[q]];

        float s[4];
#pragma unroll
        for (int j = 0; j < 4; ++j) {
            float4 a = make_float4(0.f, 0.f, 0.f, 0.f);
#pragma unroll
            for (int q = 0; q < 4; ++q) {
                a.x += wreg[j][q].x * h4[q].x;
                a.y += wreg[j][q].y * h4[q].y;
                a.z += wreg[j][q].z * h4[q].z;
                a.w += wreg[j][q].w * h4[q].w;
            }
            s[j] = hsum4(a);
        }
        // select+butterfly: lane l ends with full sum of row wr0 + (l&3)
        float A  = o1 ? s[1] : s[0], Ax = o1 ? s[0] : s[1];
        float B  = o1 ? s[3] : s[2], Bx = o1 ? s[2] : s[3];
        A += __shfl_xor(Ax, 1);
        B += __shfl_xor(Bx, 1);
        float Cv = o2 ? B : A, Cx = o2 ? A : B;
        Cv += __shfl_xor(Cx, 2);
        Cv += __shfl_xor(Cv, 4);
        Cv += __shfl_xor(Cv, 8);
        Cv += __shfl_xor(Cv, 16);
        Cv += __shfl_xor(Cv, 32);

        const float hv = fast_tanh(Cv + bh_r + uv);
        if (l < 4) {
            const unsigned long long pk =
                ((unsigned long long)(unsigned)t << 32) |
                (unsigned long long)__float_as_uint(hv);
            __hip_atomic_store(htag + (size_t)(t & 1) * H_DIM + wr0 + l, pk,
                               __ATOMIC_RELAXED, __HIP_MEMORY_SCOPE_AGENT);
        }
        __builtin_amdgcn_sched_barrier(0);   // publish must not sink below V

        // ---- hidden window: logits[t-1] from h4 registers (h^{(t)}) ----
        if (t > 0) {
            float sv[2];
#pragma unroll
            for (int m = 0; m < 2; ++m) {
                float4 a = make_float4(0.f, 0.f, 0.f, 0.f);
#pragma unroll
                for (int q = 0; q < 4; ++q) {
                    a.x += vreg[m][q].x * h4[q].x;
                    a.y += vreg[m][q].y * h4[q].y;
                    a.z += vreg[m][q].z * h4[q].z;
                    a.w += vreg[m][q].w * h4[q].w;
                }
                sv[m] = hsum4(a);
            }
            float P  = o1 ? sv[1] : sv[0], Px = o1 ? sv[0] : sv[1];
            P += __shfl_xor(Px, 1);
            P += __shfl_xor(P, 2);
            P += __shfl_xor(P, 4);
            P += __shfl_xor(P, 8);
            P += __shfl_xor(P, 16);
            P += __shfl_xor(P, 32);
            if (l < 2) out[(size_t)(t - 1) * O_DIM + vr0 + l] = P + by_r;
        }
    }

    // ---- epilogue: h_T (tag T-1, parity 1) -> out tail + logits[T-1] ----
    {
        float2 hpair = poll_pair3(
            htag + (size_t)((T_STEPS - 1) & 1) * H_DIM + 2 * tid,
            (unsigned)(T_STEPS - 1));
        if (b == 0)
            *(float2*)&out[(size_t)T_STEPS * O_DIM + 2 * tid] = hpair;

        float* hb = hl[1];             // free: loop's last stage used hl[0]
        *(float2*)&hb[wdw] = hpair;
        __syncthreads();
        float4 h4[4];
#pragma unroll
        for (int qq = 0; qq < 4; ++qq) h4[qq] = *(const float4*)&hb[rdw[qq]];
        float sv[2];
#pragma unroll
        for (int m = 0; m < 2; ++m) {
            float4 a = make_float4(0.f, 0.f, 0.f, 0.f);
#pragma unroll
            for (int qq = 0; qq < 4; ++qq) {
                a.x += vreg[m][qq].x * h4[qq].x;
                a.y += vreg[m][qq].y * h4[qq].y;
                a.z += vreg[m][qq].z * h4[qq].z;
                a.w += vreg[m][qq].w * h4[qq].w;
            }
            sv[m] = hsum4(a);
        }
        float P  = o1 ? sv[1] : sv[0], Px = o1 ? sv[0] : sv[1];
        P += __shfl_xor(Px, 1);
        P += __shfl_xor(P, 2);
        P += __shfl_xor(P, 4);
        P += __shfl_xor(P, 8);
        P += __shfl_xor(P, 16);
        P += __shfl_xor(P, 32);
        if (l < 2) out[(size_t)(T_STEPS - 1) * O_DIM + vr0 + l] = P + by_r;
    }
}

extern "C" void kernel_launch(void* const* d_in, const int* in_sizes, int n_in,
                              void* d_out, int out_size, void* d_ws, size_t ws_size,
                              hipStream_t stream) {
    const int*   xs = (const int*)d_in[0];
    const float* h0 = (const float*)d_in[1];
    const float* U  = (const float*)d_in[2];
    const float* W  = (const float*)d_in[3];
    const float* V  = (const float*)d_in[4];
    const float* bh = (const float*)d_in[5];
    const float* by = (const float*)d_in[6];
    float* out = (float*)d_out;

    // ws: htag[2][1024] u64. Poison tag 0xAAAAAAAA never matches a step in
    // [0,16384); memset re-runs on every graph replay, clearing stale tags.
    unsigned long long* htag = (unsigned long long*)d_ws;
    hipMemsetAsync(d_ws, 0xAA, 2 * H_DIM * sizeof(unsigned long long), stream);

    rnn_fused<<<NBLK, NTHR, 0, stream>>>(xs, h0, U, W, V, bh, by, out, htag);
}